// Round 12
// baseline (920.566 us; speedup 1.0000x reference)
//
#include <hip/hip_runtime.h>
#include <hip/hip_bf16.h>
#include <cmath>

#define NB   32
#define SOUT 2048
#define SIN  512
#define LOG2E 1.4426950408889634f

typedef __attribute__((ext_vector_type(8))) short bhalf8;   // 8 bf16 (4 VGPRs)
typedef __attribute__((ext_vector_type(4))) float f32x4;

__device__ inline ushort f2b(float x) {                     // f32 -> bf16 RNE
  union { float f; unsigned u; } v; v.f = x;
  unsigned r = v.u + 0x7FFFu + ((v.u >> 16) & 1u);
  return (ushort)(r >> 16);
}
__device__ inline float b2f(ushort u) {
  union { unsigned u; float f; } v; v.u = ((unsigned)u) << 16;
  return v.f;
}
__device__ inline unsigned pkt(float lo, float hi) {        // trunc-pack 2 bf16 (x>0)
  union { float f; unsigned u; } a, b; a.f = lo; b.f = hi;
  return (a.u >> 16) | (b.u & 0xFFFF0000u);
}

__device__ inline void gload16(const void* g, void* l) {    // async global->LDS, 16B/lane
  __builtin_amdgcn_global_load_lds(
      (const __attribute__((address_space(1))) void*)g,
      (__attribute__((address_space(3))) void*)l, 16, 0, 0);
}

// ---------------------------------------------------------------------------
// pts
// ---------------------------------------------------------------------------
__global__ void pts_kernel(const int* __restrict__ mArr, const int* __restrict__ nArr,
                           float* __restrict__ pts) {
  int k = blockIdx.x * blockDim.x + threadIdx.x;
  if (k >= SOUT) return;
  int m = mArr[0], n = nArr[0];
  int b = k % m, a = k / m;
  int ixb = (int)rint(45.0 * (double)b / (double)(m - 1));
  int iya = (int)rint(45.0 * (double)a / (double)(n - 1));
  const float step = 0.6f / 45.0f;
  pts[2 * k + 0] = -0.3f + step * (float)iya;
  pts[2 * k + 1] = -0.3f + step * (float)ixb;
}

// ---------------------------------------------------------------------------
// wconv: weight transposes + fused bias + gridterm.
//  0..5: W[K,N] f32 -> Wt[N,K] bf16 at fixed offsets
//  6: bhlg[384] = bh | bl | bg (f32)
//  7: gridterm[2048][128] = bup[n] + pts[2i]*Wup[128][n] + pts[2i+1]*Wup[129][n]
//  8: Wupt[128][128] bf16 = transpose(Wup[0:128][:])
// ---------------------------------------------------------------------------
__global__ __launch_bounds__(256) void wconv_kernel(
    const float* __restrict__ Wh, const float* __restrict__ Wl,
    const float* __restrict__ Wg, const float* __restrict__ Wf,
    const float* __restrict__ Wd1, const float* __restrict__ Wd2,
    const float* __restrict__ bh, const float* __restrict__ bl,
    const float* __restrict__ bg, const float* __restrict__ Wup,
    const float* __restrict__ bup, const float* __restrict__ pts,
    ushort* __restrict__ dst, float* __restrict__ fbias,
    float* __restrict__ gridterm) {
  const int which = blockIdx.y;
  int idx = blockIdx.x * 256 + threadIdx.x;
  if (which == 6) {
    if (idx < 384)
      fbias[idx] = idx < 64 ? bh[idx] : (idx < 128 ? bl[idx - 64] : bg[idx - 128]);
    return;
  }
  if (which == 7) {
    if (idx < 2048 * 128) {
      int i = idx >> 7, n = idx & 127;
      gridterm[idx] = bup[n] + pts[2 * i] * Wup[128 * 128 + n]
                             + pts[2 * i + 1] * Wup[129 * 128 + n];
    }
    return;
  }
  if (which == 8) {
    if (idx < 16384) {
      int n = idx >> 7, k = idx & 127;
      dst[294912 + n * 128 + k] = f2b(Wup[k * 128 + n]);
    }
    return;
  }
  const float* src; int K, N; long off;
  switch (which) {
    case 0: src = Wh;  K = 256; N = 64;  off = 0;      break;
    case 1: src = Wl;  K = 256; N = 64;  off = 16384;  break;
    case 2: src = Wg;  K = 256; N = 256; off = 32768;  break;
    case 3: src = Wf;  K = 256; N = 128; off = 98304;  break;
    case 4: src = Wd1; K = 512; N = 256; off = 131072; break;
    default:src = Wd2; K = 256; N = 128; off = 262144; break;
  }
  if (idx >= K * N) return;
  int n = idx / K, k = idx - n * K;
  dst[off + idx] = f2b(src[(long)k * N + n]);
}

// ---------------------------------------------------------------------------
// pconv: p f32 -> pb bf16 [32][512][128]; also writes the 4 tile-repeat
// copies into qcb's q-halves (qcb[b][i+512j][0:128], j=0..3).
// ---------------------------------------------------------------------------
__global__ __launch_bounds__(256) void pconv_kernel(
    const float* __restrict__ p, ushort* __restrict__ pb,
    ushort* __restrict__ qcb) {
  int idx = blockIdx.x * 256 + threadIdx.x;      // 0..524287, 4 elems each
  long base = (long)idx * 4;
  int b = (int)(base >> 16);                     // 512*128 per batch
  int rem = (int)(base & 65535);
  int i = rem >> 7, n = rem & 127;
  float4 v = *(const float4*)(p + base);
  ushort4 u;
  u.x = f2b(v.x); u.y = f2b(v.y); u.z = f2b(v.z); u.w = f2b(v.w);
  *(ushort4*)(pb + base) = u;
#pragma unroll
  for (int j = 0; j < 4; ++j)
    *(ushort4*)(qcb + ((long)b * 2048 + i + 512 * j) * 256 + n) = u;
}

// ---------------------------------------------------------------------------
// MFMA bf16 GEMM: acc = A[M,K] @ Wt[N,K]^T + bias, relu, epilogue by MODE.
//   MODE 0: bf16 row-major out
//   MODE 3: bf16 pmb(outv) = f2b(aux - relu(acc)); + 4 qcb q-half replicas(out2v)
//   MODE 6: qc up-half build: bias = per-row gridterm(aux);
//           outv=qcb up-half; A rows remapped (row>>11)*512+(row&511)
//   MODE 7: fused h|l|g: n<64 -> hlb; 64<=n<128 -> hlb * LOG2E;
//           n>=128 -> gt per-batch transposed (out2v)
//   MODE 8: f32 outv = relu(acc) + b2f(aux as bf16)   (final add, p1b)
// BM=128, BN=64, BK=64; 256 threads = 2x2 waves; wave tile 64x32.
// ---------------------------------------------------------------------------
template <int MODE>
__global__ __launch_bounds__(256) void mgemm(
    const ushort* __restrict__ A, const ushort* __restrict__ Wt,
    const float* __restrict__ bias, void* __restrict__ outv,
    void* __restrict__ out2v, const float* __restrict__ aux,
    int M, int N, int K) {
  __shared__ alignas(16) ushort As[128 * 64];
  __shared__ alignas(16) ushort Bs[64 * 64];
  const int tid = threadIdx.x;
  const int w = tid >> 6, lane = tid & 63, g = lane >> 4, c = lane & 15;
  const int wm = w >> 1, wn = w & 1;
  const long row0 = (long)blockIdx.y * 128;
  const int col0 = blockIdx.x * 64;
  const long Astride = (long)K * 2;
  const char* Wb = (const char*)Wt;
  const long abase = (MODE == 6) ? ((row0 >> 11) * 512 + (row0 & 511)) : row0;
  const char* Ab = (const char*)A + abase * Astride;

  f32x4 acc[4][2];
#pragma unroll
  for (int i = 0; i < 4; ++i)
#pragma unroll
    for (int j = 0; j < 2; ++j) acc[i][j] = (f32x4){0.f, 0.f, 0.f, 0.f};

  for (int k0 = 0; k0 < K; k0 += 64) {
#pragma unroll
    for (int it = 0; it < 4; ++it) {
      int o = it * 4096 + w * 1024 + lane * 16;
      int row = o >> 7, cb = o & 127;
      gload16(Ab + (long)row * Astride + k0 * 2 + (cb ^ ((row & 7) << 4)),
              (char*)As + it * 4096 + w * 1024);
    }
#pragma unroll
    for (int it = 0; it < 2; ++it) {
      int o = it * 4096 + w * 1024 + lane * 16;
      int row = o >> 7, cb = o & 127;
      gload16(Wb + (long)(col0 + row) * Astride + k0 * 2 + (cb ^ ((row & 7) << 4)),
              (char*)Bs + it * 4096 + w * 1024);
    }
    __syncthreads();
#pragma unroll
    for (int koff = 0; koff < 2; ++koff) {
      bhalf8 a[4], bfr[2];
#pragma unroll
      for (int mi = 0; mi < 4; ++mi) {
        int row = 64 * wm + 16 * mi + c;
        a[mi] = *(const bhalf8*)((const char*)As + row * 128 +
                                 ((16 * g + 64 * koff) ^ ((row & 7) << 4)));
      }
#pragma unroll
      for (int ni = 0; ni < 2; ++ni) {
        int row = 32 * wn + 16 * ni + c;
        bfr[ni] = *(const bhalf8*)((const char*)Bs + row * 128 +
                                   ((16 * g + 64 * koff) ^ ((row & 7) << 4)));
      }
#pragma unroll
      for (int mi = 0; mi < 4; ++mi)
#pragma unroll
        for (int ni = 0; ni < 2; ++ni)
          acc[mi][ni] = __builtin_amdgcn_mfma_f32_16x16x32_bf16(a[mi], bfr[ni], acc[mi][ni], 0, 0, 0);
    }
    __syncthreads();
  }

#pragma unroll
  for (int ni = 0; ni < 2; ++ni) {
    int n = col0 + 32 * wn + 16 * ni + c;
    float bn = (MODE == 6) ? 0.f : bias[n];
#pragma unroll
    for (int mi = 0; mi < 4; ++mi) {
      long m0 = row0 + 64 * wm + 16 * mi + 4 * g;
      if (MODE == 6) {
        ushort* O = (ushort*)outv;
#pragma unroll
        for (int r = 0; r < 4; ++r) {
          int i2048 = (int)((m0 + r) & 2047);
          float val = fmaxf(acc[mi][ni][r] + aux[i2048 * 128 + n], 0.f);
          O[(m0 + r) * 256 + 128 + n] = f2b(val);
        }
        continue;
      }
      float v[4];
#pragma unroll
      for (int r = 0; r < 4; ++r) v[r] = fmaxf(acc[mi][ni][r] + bn, 0.f);
      if (MODE == 0) {
        ushort* O = (ushort*)outv;
#pragma unroll
        for (int r = 0; r < 4; ++r) O[(m0 + r) * N + n] = f2b(v[r]);
      } else if (MODE == 7) {
        if (n < 128) {
          ushort* O = (ushort*)outv;
          float sc = (n >= 64) ? LOG2E : 1.0f;
#pragma unroll
          for (int r = 0; r < 4; ++r) O[(m0 + r) * 128 + n] = f2b(v[r] * sc);
        } else {
          int bb = (int)(m0 >> 11);
          int ml = (int)(m0 & 2047);
          int d = n - 128;
          ushort4 u4;
          u4.x = f2b(v[0]); u4.y = f2b(v[1]); u4.z = f2b(v[2]); u4.w = f2b(v[3]);
          *(ushort4*)((ushort*)out2v + ((long)bb * 256 + d) * 2048 + ml) = u4;
        }
      } else if (MODE == 3) {
        ushort* Opmb = (ushort*)outv;
        ushort* Oqcb = (ushort*)out2v;
#pragma unroll
        for (int r = 0; r < 4; ++r) {
          float val = aux[(m0 + r) * N + n] - v[r];
          ushort uv = f2b(val);
          Opmb[(m0 + r) * 128 + n] = uv;
          long bb = (m0 + r) >> 9;
          int ii = (int)((m0 + r) & 511);
#pragma unroll
          for (int j = 0; j < 4; ++j)
            Oqcb[(bb * 2048 + ii + 512 * j) * 256 + n] = uv;
        }
      } else {  // MODE 8: f32 out = relu(acc) + b2f(p1b)
        float* O = (float*)outv;
        const ushort* auxb = (const ushort*)aux;
#pragma unroll
        for (int r = 0; r < 4; ++r)
          O[(m0 + r) * N + n] = v[r] + b2f(auxb[(m0 + r) * N + n]);
      }
    }
  }
}

// ---------------------------------------------------------------------------
// MFMA flash attention v11 (3 blocks/CU: G single-buffered, 48KB LDS):
//   qcb[b,n,:] = bf16( qcb[b,n,:] + softmax_m(l[n]·h[m]) @ g )
// Swapped QK^T (S^T, q = lane&15); per-lane softmax; in-register P repack.
// 4 waves x 32 q-rows x all 256 d. Ht double-buffered (prefetch 1 ahead);
// Gs SINGLE-buffered: issued at iter top (WAR-safe after prior end barrier),
// drained at mid-iter barrier under QK+softmax. 2 barriers/iter.
// LDS 48KB -> 3 blocks/CU (12 waves, +50% TLP vs v10).
// ---------------------------------------------------------------------------
__global__ __launch_bounds__(256, 3) void attn_kernel(
    const ushort* __restrict__ hl, const ushort* __restrict__ gtm,
    ushort* __restrict__ qcb) {
  __shared__ alignas(16) ushort Ht[2][64 * 64];    // [kv][dqk], 8KB x2
  __shared__ alignas(16) ushort Gs[256 * 64];      // [d][kv], 32KB single

  const int tid = threadIdx.x;
  const int w = tid >> 6, lane = tid & 63, g = lane >> 4, c = lane & 15;
  const int bid = blockIdx.x;
  const int wg = (bid & 7) * 64 + (bid >> 3);      // XCD-contiguous remap (512%8==0)
  const int b = wg >> 4, nb = wg & 15;
  const float THR = 11.0f;                          // log2 units

  bhalf8 la[2][2];
#pragma unroll
  for (int qg = 0; qg < 2; ++qg) {
    const ushort* lrow = hl + ((long)b * SOUT + nb * 128 + 32 * w + 16 * qg + c) * 128 + 64 + 8 * g;
    la[qg][0] = *(const bhalf8*)(lrow);
    la[qg][1] = *(const bhalf8*)(lrow + 32);
  }

  float mold[2] = {-INFINITY, -INFINITY}, srow[2] = {0.f, 0.f};
  f32x4 oacc[16][2];
#pragma unroll
  for (int t = 0; t < 16; ++t)
#pragma unroll
    for (int qg = 0; qg < 2; ++qg) oacc[t][qg] = (f32x4){0.f, 0.f, 0.f, 0.f};

  const char* hlbase = (const char*)(hl + (long)b * SOUT * 128);  // row 256B
  const char* gtb = (const char*)(gtm + (long)b * 256 * 2048);    // row 4096B

  // ---- prologue: stage H(0) into Ht[0] ----
#pragma unroll
  for (int it = 0; it < 2; ++it) {
    int o = it * 4096 + tid * 16;
    int row = o >> 7, cb = o & 127;
    gload16(hlbase + row * 256 + (cb ^ ((row & 7) << 4)), (char*)Ht[0] + o);
  }
  __syncthreads();

  const int srcA = c + 32 * (g & 1);
  const int srcB = srcA + 16;
  const bool hi = (g >> 1) != 0;

  for (int mb = 0; mb < 32; ++mb) {
    const int buf = mb & 1;

    // ---- issue G(mb) -> Gs (WAR-safe: prior iter's end barrier passed;
    //      drains at mid-iter barrier, covered by QK+softmax) ----
#pragma unroll
    for (int it = 0; it < 8; ++it) {
      int o = it * 4096 + tid * 16;
      int row = o >> 7, cb = o & 127;
      gload16(gtb + (long)row * 4096 + mb * 128 + (cb ^ ((row & 7) << 4)),
              (char*)Gs + o);
    }
    // ---- prefetch H(mb+1) into Ht[buf^1] ----
    if (mb < 31) {
#pragma unroll
      for (int it = 0; it < 2; ++it) {
        int o = it * 4096 + tid * 16;
        int row = o >> 7, cb = o & 127;
        gload16(hlbase + ((long)(mb + 1) * 64 + row) * 256 + (cb ^ ((row & 7) << 4)),
                (char*)Ht[buf ^ 1] + o);
      }
    }

    // ---- QK^T (swapped) for both q-groups ----
    const char* hcur = (const char*)Ht[buf];
    f32x4 sacc[2][4];
#pragma unroll
    for (int qg = 0; qg < 2; ++qg)
#pragma unroll
      for (int j = 0; j < 4; ++j) sacc[qg][j] = (f32x4){0.f, 0.f, 0.f, 0.f};
#pragma unroll
    for (int j = 0; j < 4; ++j) {
      int row = 16 * j + c;
#pragma unroll
      for (int s = 0; s < 2; ++s) {
        bhalf8 hbf = *(const bhalf8*)(hcur + row * 128 +
                                      ((64 * s + 16 * g) ^ ((c & 7) << 4)));
        sacc[0][j] = __builtin_amdgcn_mfma_f32_16x16x32_bf16(hbf, la[0][s], sacc[0][j], 0, 0, 0);
        sacc[1][j] = __builtin_amdgcn_mfma_f32_16x16x32_bf16(hbf, la[1][s], sacc[1][j], 0, 0, 0);
      }
    }

    // ---- per-lane online softmax + in-register P repack ----
    bhalf8 pb[2][2];
#pragma unroll
    for (int qg = 0; qg < 2; ++qg) {
      float mloc = sacc[qg][0][0];
#pragma unroll
      for (int j = 0; j < 4; ++j)
#pragma unroll
        for (int r = 0; r < 4; ++r) mloc = fmaxf(mloc, sacc[qg][j][r]);
      mloc = fmaxf(mloc, __shfl_xor(mloc, 16));
      mloc = fmaxf(mloc, __shfl_xor(mloc, 32));
      float mnew = fmaxf(mold[qg], mloc);
      bool keep = (mloc <= mold[qg] + THR);
      float scl = keep ? 1.0f : exp2f(mold[qg] - mnew);  // first iter: exp2(-inf)=0
      mold[qg] = keep ? mold[qg] : mnew;

      float psum = 0.f;
#pragma unroll
      for (int j = 0; j < 4; ++j)
#pragma unroll
        for (int r = 0; r < 4; ++r) {
          float e = exp2f(sacc[qg][j][r] - mold[qg]);
          sacc[qg][j][r] = e; psum += e;
        }
      psum += __shfl_xor(psum, 16);
      psum += __shfl_xor(psum, 32);
      srow[qg] = srow[qg] * scl + psum;
      if (!__all(keep)) {
#pragma unroll
        for (int t = 0; t < 16; ++t) {
          oacc[t][qg][0] *= scl; oacc[t][qg][1] *= scl;
          oacc[t][qg][2] *= scl; oacc[t][qg][3] *= scl;
        }
      }

#pragma unroll
      for (int s2 = 0; s2 < 2; ++s2) {
        int j2 = 2 * s2;
        unsigned wA0 = pkt(sacc[qg][j2][0], sacc[qg][j2][1]);
        unsigned wA1 = pkt(sacc[qg][j2][2], sacc[qg][j2][3]);
        unsigned wB0 = pkt(sacc[qg][j2 + 1][0], sacc[qg][j2 + 1][1]);
        unsigned wB1 = pkt(sacc[qg][j2 + 1][2], sacc[qg][j2 + 1][3]);
        unsigned a0A = (unsigned)__shfl((int)wA0, srcA);
        unsigned b0A = (unsigned)__shfl((int)wB0, srcA);
        unsigned a1A = (unsigned)__shfl((int)wA1, srcA);
        unsigned b1A = (unsigned)__shfl((int)wB1, srcA);
        unsigned a0B = (unsigned)__shfl((int)wA0, srcB);
        unsigned b0B = (unsigned)__shfl((int)wB0, srcB);
        unsigned a1B = (unsigned)__shfl((int)wA1, srcB);
        unsigned b1B = (unsigned)__shfl((int)wB1, srcB);
        union { unsigned u[4]; bhalf8 v; } pw;
        pw.u[0] = hi ? b0A : a0A;
        pw.u[1] = hi ? b1A : a1A;
        pw.u[2] = hi ? b0B : a0B;
        pw.u[3] = hi ? b1B : a1B;
        pb[qg][s2] = pw.v;
      }
    }

    __syncthreads();   // b1: G(mb) + H(mb+1) staging drained

    // ---- PV over all 256 d ----
#pragma unroll
    for (int s2 = 0; s2 < 2; ++s2) {
#pragma unroll
      for (int t = 0; t < 16; ++t) {
        int row = 16 * t + c;
        bhalf8 ga = *(const bhalf8*)((const char*)Gs + row * 128 +
                                     ((64 * s2 + 16 * g) ^ ((c & 7) << 4)));
        oacc[t][0] = __builtin_amdgcn_mfma_f32_16x16x32_bf16(ga, pb[0][s2], oacc[t][0], 0, 0, 0);
        oacc[t][1] = __builtin_amdgcn_mfma_f32_16x16x32_bf16(ga, pb[1][s2], oacc[t][1], 0, 0, 0);
      }
    }

    __syncthreads();   // b2: all waves done reading Gs (next iter overwrites)
  }

  // ---- epilogue ----
#pragma unroll
  for (int qg = 0; qg < 2; ++qg) {
    float inv = 1.0f / srow[qg];
    long qrow = ((long)b * SOUT + nb * 128 + 32 * w + 16 * qg + c) * 256;
#pragma unroll
    for (int t = 0; t < 16; ++t) {
      long addr = qrow + 16 * t + 4 * g;
      ushort4 cur = *(const ushort4*)(qcb + addr);
      cur.x = f2b(b2f(cur.x) + oacc[t][qg][0] * inv);
      cur.y = f2b(b2f(cur.y) + oacc[t][qg][1] * inv);
      cur.z = f2b(b2f(cur.z) + oacc[t][qg][2] * inv);
      cur.w = f2b(b2f(cur.w) + oacc[t][qg][3] * inv);
      *(ushort4*)(qcb + addr) = cur;
    }
  }
}

// ---------------------------------------------------------------------------
extern "C" void kernel_launch(void* const* d_in, const int* in_sizes, int n_in,
                              void* d_out, int out_size, void* d_ws, size_t ws_size,
                              hipStream_t stream) {
  (void)in_sizes; (void)n_in; (void)out_size; (void)ws_size;
  const float* p   = (const float*)d_in[0];
  const float* Wh  = (const float*)d_in[1];
  const float* bh  = (const float*)d_in[2];
  const float* Wl  = (const float*)d_in[3];
  const float* bl  = (const float*)d_in[4];
  const float* Wg  = (const float*)d_in[5];
  const float* bg  = (const float*)d_in[6];
  const float* Wf  = (const float*)d_in[7];
  const float* bf  = (const float*)d_in[8];
  const float* Wup = (const float*)d_in[9];
  const float* bup = (const float*)d_in[10];
  const float* Wd1 = (const float*)d_in[11];
  const float* bd1 = (const float*)d_in[12];
  const float* Wd2 = (const float*)d_in[13];
  const float* bd2 = (const float*)d_in[14];
  const int* mArr  = (const int*)d_in[15];
  const int* nArr  = (const int*)d_in[16];
  float* out = (float*)d_out;

  // workspace layout
  float* ws       = (float*)d_ws;
  float* pts      = ws;                         // 4,096 f32
  float* bhlg     = ws + 4096;                  // 512 f32 (384 used)
  float* gridterm = bhlg + 512;                 // 262,144 f32
  ushort* qcb  = (ushort*)(gridterm + 262144);  // 16,777,216 us
  ushort* hlb  = qcb + 16777216;                //  8,388,608 us
  ushort* gt   = hlb + 8388608;                 // 16,777,216 us
  ushort* p1b  = gt + 16777216;                 //  8,388,608 us
  ushort* d1b  = p1b + 8388608;                 //  4,194,304 us
  ushort* pb   = d1b + 4194304;                 //  2,097,152 us
  ushort* pmb  = pb + 2097152;                  //  2,097,152 us
  ushort* wts  = pmb + 2097152;                 //    311,296 us
  ushort* Wft  = wts + 98304;
  ushort* Wd1t = wts + 131072;
  ushort* Wd2t = wts + 262144;
  ushort* Wupt = wts + 294912;

  pts_kernel<<<8, 256, 0, stream>>>(mArr, nArr, pts);
  wconv_kernel<<<dim3(1024, 9), 256, 0, stream>>>(
      Wh, Wl, Wg, Wf, Wd1, Wd2, bh, bl, bg, Wup, bup, pts, wts, bhlg, gridterm);

  // ---------------- up #1 ----------------
  pconv_kernel<<<2048, 256, 0, stream>>>(p, pb, qcb);
  mgemm<6><<<dim3(2, 512), 256, 0, stream>>>(pb, Wupt, bhlg, qcb, nullptr, gridterm, 65536, 128, 128);
  mgemm<7><<<dim3(6, 512), 256, 0, stream>>>(qcb, wts, bhlg, hlb, gt, nullptr, 65536, 384, 256);
  attn_kernel<<<512, 256, 0, stream>>>(hlb, gt, qcb);
  mgemm<0><<<dim3(2, 512), 256, 0, stream>>>(qcb, Wft, bf, p1b, nullptr, nullptr, 65536, 128, 256);

  // ---------------- down ----------------
  mgemm<0><<<dim3(4, 128), 256, 0, stream>>>(p1b, Wd1t, bd1, d1b, nullptr, nullptr, 16384, 256, 512);
  mgemm<3><<<dim3(2, 128), 256, 0, stream>>>(d1b, Wd2t, bd2, pmb, qcb, p, 16384, 128, 256);

  // ---------------- up #2 + final add ----------------
  mgemm<6><<<dim3(2, 512), 256, 0, stream>>>(pmb, Wupt, bhlg, qcb, nullptr, gridterm, 65536, 128, 128);
  mgemm<7><<<dim3(6, 512), 256, 0, stream>>>(qcb, wts, bhlg, hlb, gt, nullptr, 65536, 384, 256);
  attn_kernel<<<512, 256, 0, stream>>>(hlb, gt, qcb);
  mgemm<8><<<dim3(2, 512), 256, 0, stream>>>(qcb, Wft, bf, out, nullptr, (const float*)p1b, 65536, 128, 256);
}

// Round 13
// 411.881 us; speedup vs baseline: 2.2350x; 2.2350x over previous
//
#include <hip/hip_runtime.h>
#include <hip/hip_bf16.h>
#include <cmath>

#define NB   32
#define SOUT 2048
#define SIN  512
#define LOG2E 1.4426950408889634f

typedef __attribute__((ext_vector_type(8))) short bhalf8;   // 8 bf16 (4 VGPRs)
typedef __attribute__((ext_vector_type(4))) float f32x4;

__device__ inline ushort f2b(float x) {                     // f32 -> bf16 RNE
  union { float f; unsigned u; } v; v.f = x;
  unsigned r = v.u + 0x7FFFu + ((v.u >> 16) & 1u);
  return (ushort)(r >> 16);
}
__device__ inline float b2f(ushort u) {
  union { unsigned u; float f; } v; v.u = ((unsigned)u) << 16;
  return v.f;
}
__device__ inline unsigned pkt(float lo, float hi) {        // trunc-pack 2 bf16 (x>0)
  union { float f; unsigned u; } a, b; a.f = lo; b.f = hi;
  return (a.u >> 16) | (b.u & 0xFFFF0000u);
}

__device__ inline void gload16(const void* g, void* l) {    // async global->LDS, 16B/lane
  __builtin_amdgcn_global_load_lds(
      (const __attribute__((address_space(1))) void*)g,
      (__attribute__((address_space(3))) void*)l, 16, 0, 0);
}

// ---------------------------------------------------------------------------
// pts
// ---------------------------------------------------------------------------
__global__ void pts_kernel(const int* __restrict__ mArr, const int* __restrict__ nArr,
                           float* __restrict__ pts) {
  int k = blockIdx.x * blockDim.x + threadIdx.x;
  if (k >= SOUT) return;
  int m = mArr[0], n = nArr[0];
  int b = k % m, a = k / m;
  int ixb = (int)rint(45.0 * (double)b / (double)(m - 1));
  int iya = (int)rint(45.0 * (double)a / (double)(n - 1));
  const float step = 0.6f / 45.0f;
  pts[2 * k + 0] = -0.3f + step * (float)iya;
  pts[2 * k + 1] = -0.3f + step * (float)ixb;
}

// ---------------------------------------------------------------------------
// wconv: weight transposes + fused bias + gridterm.
//  0..5: W[K,N] f32 -> Wt[N,K] bf16 at fixed offsets
//  6: bhlg[384] = bh | bl | bg (f32)
//  7: gridterm[2048][128] = bup[n] + pts[2i]*Wup[128][n] + pts[2i+1]*Wup[129][n]
//  8: Wupt[128][128] bf16 = transpose(Wup[0:128][:])
// ---------------------------------------------------------------------------
__global__ __launch_bounds__(256) void wconv_kernel(
    const float* __restrict__ Wh, const float* __restrict__ Wl,
    const float* __restrict__ Wg, const float* __restrict__ Wf,
    const float* __restrict__ Wd1, const float* __restrict__ Wd2,
    const float* __restrict__ bh, const float* __restrict__ bl,
    const float* __restrict__ bg, const float* __restrict__ Wup,
    const float* __restrict__ bup, const float* __restrict__ pts,
    ushort* __restrict__ dst, float* __restrict__ fbias,
    float* __restrict__ gridterm) {
  const int which = blockIdx.y;
  int idx = blockIdx.x * 256 + threadIdx.x;
  if (which == 6) {
    if (idx < 384)
      fbias[idx] = idx < 64 ? bh[idx] : (idx < 128 ? bl[idx - 64] : bg[idx - 128]);
    return;
  }
  if (which == 7) {
    if (idx < 2048 * 128) {
      int i = idx >> 7, n = idx & 127;
      gridterm[idx] = bup[n] + pts[2 * i] * Wup[128 * 128 + n]
                             + pts[2 * i + 1] * Wup[129 * 128 + n];
    }
    return;
  }
  if (which == 8) {
    if (idx < 16384) {
      int n = idx >> 7, k = idx & 127;
      dst[294912 + n * 128 + k] = f2b(Wup[k * 128 + n]);
    }
    return;
  }
  const float* src; int K, N; long off;
  switch (which) {
    case 0: src = Wh;  K = 256; N = 64;  off = 0;      break;
    case 1: src = Wl;  K = 256; N = 64;  off = 16384;  break;
    case 2: src = Wg;  K = 256; N = 256; off = 32768;  break;
    case 3: src = Wf;  K = 256; N = 128; off = 98304;  break;
    case 4: src = Wd1; K = 512; N = 256; off = 131072; break;
    default:src = Wd2; K = 256; N = 128; off = 262144; break;
  }
  if (idx >= K * N) return;
  int n = idx / K, k = idx - n * K;
  dst[off + idx] = f2b(src[(long)k * N + n]);
}

// ---------------------------------------------------------------------------
// pconv: p f32 -> pb bf16 [32][512][128]; also writes the 4 tile-repeat
// copies into qcb's q-halves (qcb[b][i+512j][0:128], j=0..3).
// ---------------------------------------------------------------------------
__global__ __launch_bounds__(256) void pconv_kernel(
    const float* __restrict__ p, ushort* __restrict__ pb,
    ushort* __restrict__ qcb) {
  int idx = blockIdx.x * 256 + threadIdx.x;      // 0..524287, 4 elems each
  long base = (long)idx * 4;
  int b = (int)(base >> 16);                     // 512*128 per batch
  int rem = (int)(base & 65535);
  int i = rem >> 7, n = rem & 127;
  float4 v = *(const float4*)(p + base);
  ushort4 u;
  u.x = f2b(v.x); u.y = f2b(v.y); u.z = f2b(v.z); u.w = f2b(v.w);
  *(ushort4*)(pb + base) = u;
#pragma unroll
  for (int j = 0; j < 4; ++j)
    *(ushort4*)(qcb + ((long)b * 2048 + i + 512 * j) * 256 + n) = u;
}

// ---------------------------------------------------------------------------
// MFMA bf16 GEMM: acc = A[M,K] @ Wt[N,K]^T + bias, relu, epilogue by MODE.
//   MODE 0: bf16 row-major out
//   MODE 3: bf16 pmb(outv) = f2b(aux - relu(acc)); + 4 qcb q-half replicas(out2v)
//   MODE 6: qc up-half build: bias = per-row gridterm(aux);
//           outv=qcb up-half; A rows remapped (row>>11)*512+(row&511)
//   MODE 7: fused h|l|g: n<64 -> hlb; 64<=n<128 -> hlb * LOG2E;
//           n>=128 -> gt per-batch transposed (out2v)
//   MODE 8: f32 outv = relu(acc) + b2f(aux as bf16)   (final add, p1b)
// BM=128, BN=64, BK=64; 256 threads = 2x2 waves; wave tile 64x32.
// ---------------------------------------------------------------------------
template <int MODE>
__global__ __launch_bounds__(256) void mgemm(
    const ushort* __restrict__ A, const ushort* __restrict__ Wt,
    const float* __restrict__ bias, void* __restrict__ outv,
    void* __restrict__ out2v, const float* __restrict__ aux,
    int M, int N, int K) {
  __shared__ alignas(16) ushort As[128 * 64];
  __shared__ alignas(16) ushort Bs[64 * 64];
  const int tid = threadIdx.x;
  const int w = tid >> 6, lane = tid & 63, g = lane >> 4, c = lane & 15;
  const int wm = w >> 1, wn = w & 1;
  const long row0 = (long)blockIdx.y * 128;
  const int col0 = blockIdx.x * 64;
  const long Astride = (long)K * 2;
  const char* Wb = (const char*)Wt;
  const long abase = (MODE == 6) ? ((row0 >> 11) * 512 + (row0 & 511)) : row0;
  const char* Ab = (const char*)A + abase * Astride;

  f32x4 acc[4][2];
#pragma unroll
  for (int i = 0; i < 4; ++i)
#pragma unroll
    for (int j = 0; j < 2; ++j) acc[i][j] = (f32x4){0.f, 0.f, 0.f, 0.f};

  for (int k0 = 0; k0 < K; k0 += 64) {
#pragma unroll
    for (int it = 0; it < 4; ++it) {
      int o = it * 4096 + w * 1024 + lane * 16;
      int row = o >> 7, cb = o & 127;
      gload16(Ab + (long)row * Astride + k0 * 2 + (cb ^ ((row & 7) << 4)),
              (char*)As + it * 4096 + w * 1024);
    }
#pragma unroll
    for (int it = 0; it < 2; ++it) {
      int o = it * 4096 + w * 1024 + lane * 16;
      int row = o >> 7, cb = o & 127;
      gload16(Wb + (long)(col0 + row) * Astride + k0 * 2 + (cb ^ ((row & 7) << 4)),
              (char*)Bs + it * 4096 + w * 1024);
    }
    __syncthreads();
#pragma unroll
    for (int koff = 0; koff < 2; ++koff) {
      bhalf8 a[4], bfr[2];
#pragma unroll
      for (int mi = 0; mi < 4; ++mi) {
        int row = 64 * wm + 16 * mi + c;
        a[mi] = *(const bhalf8*)((const char*)As + row * 128 +
                                 ((16 * g + 64 * koff) ^ ((row & 7) << 4)));
      }
#pragma unroll
      for (int ni = 0; ni < 2; ++ni) {
        int row = 32 * wn + 16 * ni + c;
        bfr[ni] = *(const bhalf8*)((const char*)Bs + row * 128 +
                                   ((16 * g + 64 * koff) ^ ((row & 7) << 4)));
      }
#pragma unroll
      for (int mi = 0; mi < 4; ++mi)
#pragma unroll
        for (int ni = 0; ni < 2; ++ni)
          acc[mi][ni] = __builtin_amdgcn_mfma_f32_16x16x32_bf16(a[mi], bfr[ni], acc[mi][ni], 0, 0, 0);
    }
    __syncthreads();
  }

#pragma unroll
  for (int ni = 0; ni < 2; ++ni) {
    int n = col0 + 32 * wn + 16 * ni + c;
    float bn = (MODE == 6) ? 0.f : bias[n];
#pragma unroll
    for (int mi = 0; mi < 4; ++mi) {
      long m0 = row0 + 64 * wm + 16 * mi + 4 * g;
      if (MODE == 6) {
        ushort* O = (ushort*)outv;
#pragma unroll
        for (int r = 0; r < 4; ++r) {
          int i2048 = (int)((m0 + r) & 2047);
          float val = fmaxf(acc[mi][ni][r] + aux[i2048 * 128 + n], 0.f);
          O[(m0 + r) * 256 + 128 + n] = f2b(val);
        }
        continue;
      }
      float v[4];
#pragma unroll
      for (int r = 0; r < 4; ++r) v[r] = fmaxf(acc[mi][ni][r] + bn, 0.f);
      if (MODE == 0) {
        ushort* O = (ushort*)outv;
#pragma unroll
        for (int r = 0; r < 4; ++r) O[(m0 + r) * N + n] = f2b(v[r]);
      } else if (MODE == 7) {
        if (n < 128) {
          ushort* O = (ushort*)outv;
          float sc = (n >= 64) ? LOG2E : 1.0f;
#pragma unroll
          for (int r = 0; r < 4; ++r) O[(m0 + r) * 128 + n] = f2b(v[r] * sc);
        } else {
          int bb = (int)(m0 >> 11);
          int ml = (int)(m0 & 2047);
          int d = n - 128;
          ushort4 u4;
          u4.x = f2b(v[0]); u4.y = f2b(v[1]); u4.z = f2b(v[2]); u4.w = f2b(v[3]);
          *(ushort4*)((ushort*)out2v + ((long)bb * 256 + d) * 2048 + ml) = u4;
        }
      } else if (MODE == 3) {
        ushort* Opmb = (ushort*)outv;
        ushort* Oqcb = (ushort*)out2v;
#pragma unroll
        for (int r = 0; r < 4; ++r) {
          float val = aux[(m0 + r) * N + n] - v[r];
          ushort uv = f2b(val);
          Opmb[(m0 + r) * 128 + n] = uv;
          long bb = (m0 + r) >> 9;
          int ii = (int)((m0 + r) & 511);
#pragma unroll
          for (int j = 0; j < 4; ++j)
            Oqcb[(bb * 2048 + ii + 512 * j) * 256 + n] = uv;
        }
      } else {  // MODE 8: f32 out = relu(acc) + b2f(p1b)
        float* O = (float*)outv;
        const ushort* auxb = (const ushort*)aux;
#pragma unroll
        for (int r = 0; r < 4; ++r)
          O[(m0 + r) * N + n] = v[r] + b2f(auxb[(m0 + r) * N + n]);
      }
    }
  }
}

// ---------------------------------------------------------------------------
// MFMA flash attention v10 (proven 135us config; reverted from v11's
// register-spill disaster): 2x LDS reuse, wave = 32q x full 256d.
//   qcb[b,n,:] = bf16( qcb[b,n,:] + softmax_m(l[n]·h[m]) @ g )
// Swapped QK^T (S^T, q = lane&15); per-lane softmax; in-register P repack.
// 4 waves x 32 q-rows x all 256 d. H+G^T double-buffered LDS (80KB),
// coalesced global_load_lds prefetch 1 iter ahead, ONE barrier per iter.
// launch_bounds(256,2): occupancy is REGISTER-capped (acc 128 + sacc 32 ->
// ~250 unified regs/wave = 2 waves/SIMD); do NOT request 3 (spills, R12).
// ---------------------------------------------------------------------------
__global__ __launch_bounds__(256, 2) void attn_kernel(
    const ushort* __restrict__ hl, const ushort* __restrict__ gtm,
    ushort* __restrict__ qcb) {
  __shared__ alignas(16) ushort Ht[2][64 * 64];    // [kv][dqk], 8KB each
  __shared__ alignas(16) ushort Gs[2][256 * 64];   // [d][kv],  32KB each

  const int tid = threadIdx.x;
  const int w = tid >> 6, lane = tid & 63, g = lane >> 4, c = lane & 15;
  const int bid = blockIdx.x;
  const int wg = (bid & 7) * 64 + (bid >> 3);      // XCD-contiguous remap (512%8==0)
  const int b = wg >> 4, nb = wg & 15;
  const float THR = 11.0f;                          // log2 units

  bhalf8 la[2][2];
#pragma unroll
  for (int qg = 0; qg < 2; ++qg) {
    const ushort* lrow = hl + ((long)b * SOUT + nb * 128 + 32 * w + 16 * qg + c) * 128 + 64 + 8 * g;
    la[qg][0] = *(const bhalf8*)(lrow);
    la[qg][1] = *(const bhalf8*)(lrow + 32);
  }

  float mold[2] = {-INFINITY, -INFINITY}, srow[2] = {0.f, 0.f};
  f32x4 oacc[16][2];
#pragma unroll
  for (int t = 0; t < 16; ++t)
#pragma unroll
    for (int qg = 0; qg < 2; ++qg) oacc[t][qg] = (f32x4){0.f, 0.f, 0.f, 0.f};

  const char* hlbase = (const char*)(hl + (long)b * SOUT * 128);  // row 256B
  const char* gtb = (const char*)(gtm + (long)b * 256 * 2048);    // row 4096B

  {
#pragma unroll
    for (int it = 0; it < 2; ++it) {
      int o = it * 4096 + tid * 16;
      int row = o >> 7, cb = o & 127;
      gload16(hlbase + row * 256 + (cb ^ ((row & 7) << 4)), (char*)Ht[0] + o);
    }
#pragma unroll
    for (int it = 0; it < 8; ++it) {
      int o = it * 4096 + tid * 16;
      int row = o >> 7, cb = o & 127;
      gload16(gtb + (long)row * 4096 + (cb ^ ((row & 7) << 4)), (char*)Gs[0] + o);
    }
  }
  __syncthreads();

  const int srcA = c + 32 * (g & 1);
  const int srcB = srcA + 16;
  const bool hi = (g >> 1) != 0;

  for (int mb = 0; mb < 32; ++mb) {
    const int buf = mb & 1;

    if (mb < 31) {
#pragma unroll
      for (int it = 0; it < 2; ++it) {
        int o = it * 4096 + tid * 16;
        int row = o >> 7, cb = o & 127;
        gload16(hlbase + ((long)(mb + 1) * 64 + row) * 256 + (cb ^ ((row & 7) << 4)),
                (char*)Ht[buf ^ 1] + o);
      }
#pragma unroll
      for (int it = 0; it < 8; ++it) {
        int o = it * 4096 + tid * 16;
        int row = o >> 7, cb = o & 127;
        gload16(gtb + (long)row * 4096 + (mb + 1) * 128 + (cb ^ ((row & 7) << 4)),
                (char*)Gs[buf ^ 1] + o);
      }
    }

    const char* hcur = (const char*)Ht[buf];
    f32x4 sacc[2][4];
#pragma unroll
    for (int qg = 0; qg < 2; ++qg)
#pragma unroll
      for (int j = 0; j < 4; ++j) sacc[qg][j] = (f32x4){0.f, 0.f, 0.f, 0.f};
#pragma unroll
    for (int j = 0; j < 4; ++j) {
      int row = 16 * j + c;
#pragma unroll
      for (int s = 0; s < 2; ++s) {
        bhalf8 hbf = *(const bhalf8*)(hcur + row * 128 +
                                      ((64 * s + 16 * g) ^ ((c & 7) << 4)));
        sacc[0][j] = __builtin_amdgcn_mfma_f32_16x16x32_bf16(hbf, la[0][s], sacc[0][j], 0, 0, 0);
        sacc[1][j] = __builtin_amdgcn_mfma_f32_16x16x32_bf16(hbf, la[1][s], sacc[1][j], 0, 0, 0);
      }
    }

    bhalf8 pb[2][2];
#pragma unroll
    for (int qg = 0; qg < 2; ++qg) {
      float mloc = sacc[qg][0][0];
#pragma unroll
      for (int j = 0; j < 4; ++j)
#pragma unroll
        for (int r = 0; r < 4; ++r) mloc = fmaxf(mloc, sacc[qg][j][r]);
      mloc = fmaxf(mloc, __shfl_xor(mloc, 16));
      mloc = fmaxf(mloc, __shfl_xor(mloc, 32));
      float mnew = fmaxf(mold[qg], mloc);
      bool keep = (mloc <= mold[qg] + THR);
      float scl = keep ? 1.0f : exp2f(mold[qg] - mnew);
      mold[qg] = keep ? mold[qg] : mnew;

      float psum = 0.f;
#pragma unroll
      for (int j = 0; j < 4; ++j)
#pragma unroll
        for (int r = 0; r < 4; ++r) {
          float e = exp2f(sacc[qg][j][r] - mold[qg]);
          sacc[qg][j][r] = e; psum += e;
        }
      psum += __shfl_xor(psum, 16);
      psum += __shfl_xor(psum, 32);
      srow[qg] = srow[qg] * scl + psum;
      if (!__all(keep)) {
#pragma unroll
        for (int t = 0; t < 16; ++t) {
          oacc[t][qg][0] *= scl; oacc[t][qg][1] *= scl;
          oacc[t][qg][2] *= scl; oacc[t][qg][3] *= scl;
        }
      }

#pragma unroll
      for (int s2 = 0; s2 < 2; ++s2) {
        int j2 = 2 * s2;
        unsigned wA0 = pkt(sacc[qg][j2][0], sacc[qg][j2][1]);
        unsigned wA1 = pkt(sacc[qg][j2][2], sacc[qg][j2][3]);
        unsigned wB0 = pkt(sacc[qg][j2 + 1][0], sacc[qg][j2 + 1][1]);
        unsigned wB1 = pkt(sacc[qg][j2 + 1][2], sacc[qg][j2 + 1][3]);
        unsigned a0A = (unsigned)__shfl((int)wA0, srcA);
        unsigned b0A = (unsigned)__shfl((int)wB0, srcA);
        unsigned a1A = (unsigned)__shfl((int)wA1, srcA);
        unsigned b1A = (unsigned)__shfl((int)wB1, srcA);
        unsigned a0B = (unsigned)__shfl((int)wA0, srcB);
        unsigned b0B = (unsigned)__shfl((int)wB0, srcB);
        unsigned a1B = (unsigned)__shfl((int)wA1, srcB);
        unsigned b1B = (unsigned)__shfl((int)wB1, srcB);
        union { unsigned u[4]; bhalf8 v; } pw;
        pw.u[0] = hi ? b0A : a0A;
        pw.u[1] = hi ? b1A : a1A;
        pw.u[2] = hi ? b0B : a0B;
        pw.u[3] = hi ? b1B : a1B;
        pb[qg][s2] = pw.v;
      }
    }

    const char* gcur = (const char*)Gs[buf];
#pragma unroll
    for (int s2 = 0; s2 < 2; ++s2) {
#pragma unroll
      for (int t = 0; t < 16; ++t) {
        int row = 16 * t + c;
        bhalf8 ga = *(const bhalf8*)(gcur + row * 128 +
                                     ((64 * s2 + 16 * g) ^ ((c & 7) << 4)));
        oacc[t][0] = __builtin_amdgcn_mfma_f32_16x16x32_bf16(ga, pb[0][s2], oacc[t][0], 0, 0, 0);
        oacc[t][1] = __builtin_amdgcn_mfma_f32_16x16x32_bf16(ga, pb[1][s2], oacc[t][1], 0, 0, 0);
      }
    }

    __syncthreads();
  }

#pragma unroll
  for (int qg = 0; qg < 2; ++qg) {
    float inv = 1.0f / srow[qg];
    long qrow = ((long)b * SOUT + nb * 128 + 32 * w + 16 * qg + c) * 256;
#pragma unroll
    for (int t = 0; t < 16; ++t) {
      long addr = qrow + 16 * t + 4 * g;
      ushort4 cur = *(const ushort4*)(qcb + addr);
      cur.x = f2b(b2f(cur.x) + oacc[t][qg][0] * inv);
      cur.y = f2b(b2f(cur.y) + oacc[t][qg][1] * inv);
      cur.z = f2b(b2f(cur.z) + oacc[t][qg][2] * inv);
      cur.w = f2b(b2f(cur.w) + oacc[t][qg][3] * inv);
      *(ushort4*)(qcb + addr) = cur;
    }
  }
}

// ---------------------------------------------------------------------------
extern "C" void kernel_launch(void* const* d_in, const int* in_sizes, int n_in,
                              void* d_out, int out_size, void* d_ws, size_t ws_size,
                              hipStream_t stream) {
  (void)in_sizes; (void)n_in; (void)out_size; (void)ws_size;
  const float* p   = (const float*)d_in[0];
  const float* Wh  = (const float*)d_in[1];
  const float* bh  = (const float*)d_in[2];
  const float* Wl  = (const float*)d_in[3];
  const float* bl  = (const float*)d_in[4];
  const float* Wg  = (const float*)d_in[5];
  const float* bg  = (const float*)d_in[6];
  const float* Wf  = (const float*)d_in[7];
  const float* bf  = (const float*)d_in[8];
  const float* Wup = (const float*)d_in[9];
  const float* bup = (const float*)d_in[10];
  const float* Wd1 = (const float*)d_in[11];
  const float* bd1 = (const float*)d_in[12];
  const float* Wd2 = (const float*)d_in[13];
  const float* bd2 = (const float*)d_in[14];
  const int* mArr  = (const int*)d_in[15];
  const int* nArr  = (const int*)d_in[16];
  float* out = (float*)d_out;

  // workspace layout
  float* ws       = (float*)d_ws;
  float* pts      = ws;                         // 4,096 f32
  float* bhlg     = ws + 4096;                  // 512 f32 (384 used)
  float* gridterm = bhlg + 512;                 // 262,144 f32
  ushort* qcb  = (ushort*)(gridterm + 262144);  // 16,777,216 us
  ushort* hlb  = qcb + 16777216;                //  8,388,608 us
  ushort* gt   = hlb + 8388608;                 // 16,777,216 us
  ushort* p1b  = gt + 16777216;                 //  8,388,608 us
  ushort* d1b  = p1b + 8388608;                 //  4,194,304 us
  ushort* pb   = d1b + 4194304;                 //  2,097,152 us
  ushort* pmb  = pb + 2097152;                  //  2,097,152 us
  ushort* wts  = pmb + 2097152;                 //    311,296 us
  ushort* Wft  = wts + 98304;
  ushort* Wd1t = wts + 131072;
  ushort* Wd2t = wts + 262144;
  ushort* Wupt = wts + 294912;

  pts_kernel<<<8, 256, 0, stream>>>(mArr, nArr, pts);
  wconv_kernel<<<dim3(1024, 9), 256, 0, stream>>>(
      Wh, Wl, Wg, Wf, Wd1, Wd2, bh, bl, bg, Wup, bup, pts, wts, bhlg, gridterm);

  // ---------------- up #1 ----------------
  pconv_kernel<<<2048, 256, 0, stream>>>(p, pb, qcb);
  mgemm<6><<<dim3(2, 512), 256, 0, stream>>>(pb, Wupt, bhlg, qcb, nullptr, gridterm, 65536, 128, 128);
  mgemm<7><<<dim3(6, 512), 256, 0, stream>>>(qcb, wts, bhlg, hlb, gt, nullptr, 65536, 384, 256);
  attn_kernel<<<512, 256, 0, stream>>>(hlb, gt, qcb);
  mgemm<0><<<dim3(2, 512), 256, 0, stream>>>(qcb, Wft, bf, p1b, nullptr, nullptr, 65536, 128, 256);

  // ---------------- down ----------------
  mgemm<0><<<dim3(4, 128), 256, 0, stream>>>(p1b, Wd1t, bd1, d1b, nullptr, nullptr, 16384, 256, 512);
  mgemm<3><<<dim3(2, 128), 256, 0, stream>>>(d1b, Wd2t, bd2, pmb, qcb, p, 16384, 128, 256);

  // ---------------- up #2 + final add ----------------
  mgemm<6><<<dim3(2, 512), 256, 0, stream>>>(pmb, Wupt, bhlg, qcb, nullptr, gridterm, 65536, 128, 128);
  mgemm<7><<<dim3(6, 512), 256, 0, stream>>>(qcb, wts, bhlg, hlb, gt, nullptr, 65536, 384, 256);
  attn_kernel<<<512, 256, 0, stream>>>(hlb, gt, qcb);
  mgemm<8><<<dim3(2, 512), 256, 0, stream>>>(qcb, Wft, bf, out, nullptr, (const float*)p1b, 65536, 128, 256);
}

// Round 14
// 400.184 us; speedup vs baseline: 2.3004x; 1.0292x over previous
//
#include <hip/hip_runtime.h>
#include <hip/hip_bf16.h>
#include <cmath>

#define NB   32
#define SOUT 2048
#define SIN  512
#define LOG2E 1.4426950408889634f

typedef __attribute__((ext_vector_type(8))) short bhalf8;   // 8 bf16 (4 VGPRs)
typedef __attribute__((ext_vector_type(4))) float f32x4;

__device__ inline ushort f2b(float x) {                     // f32 -> bf16 RNE
  union { float f; unsigned u; } v; v.f = x;
  unsigned r = v.u + 0x7FFFu + ((v.u >> 16) & 1u);
  return (ushort)(r >> 16);
}
__device__ inline float b2f(ushort u) {
  union { unsigned u; float f; } v; v.u = ((unsigned)u) << 16;
  return v.f;
}
__device__ inline unsigned pkt(float lo, float hi) {        // trunc-pack 2 bf16 (x>0)
  union { float f; unsigned u; } a, b; a.f = lo; b.f = hi;
  return (a.u >> 16) | (b.u & 0xFFFF0000u);
}

__device__ inline void gload16(const void* g, void* l) {    // async global->LDS, 16B/lane
  __builtin_amdgcn_global_load_lds(
      (const __attribute__((address_space(1))) void*)g,
      (__attribute__((address_space(3))) void*)l, 16, 0, 0);
}

// ---------------------------------------------------------------------------
// pts
// ---------------------------------------------------------------------------
__global__ void pts_kernel(const int* __restrict__ mArr, const int* __restrict__ nArr,
                           float* __restrict__ pts) {
  int k = blockIdx.x * blockDim.x + threadIdx.x;
  if (k >= SOUT) return;
  int m = mArr[0], n = nArr[0];
  int b = k % m, a = k / m;
  int ixb = (int)rint(45.0 * (double)b / (double)(m - 1));
  int iya = (int)rint(45.0 * (double)a / (double)(n - 1));
  const float step = 0.6f / 45.0f;
  pts[2 * k + 0] = -0.3f + step * (float)iya;
  pts[2 * k + 1] = -0.3f + step * (float)ixb;
}

// ---------------------------------------------------------------------------
// wconv: weight transposes + fused bias + gridterm.
//  0..5: W[K,N] f32 -> Wt[N,K] bf16 at fixed offsets
//  6: bhlg[384] = bh | bl | bg (f32)
//  7: gridterm[2048][128] = bup[n] + pts[2i]*Wup[128][n] + pts[2i+1]*Wup[129][n]
//  8: Wupt[128][128] bf16 = transpose(Wup[0:128][:])
// ---------------------------------------------------------------------------
__global__ __launch_bounds__(256) void wconv_kernel(
    const float* __restrict__ Wh, const float* __restrict__ Wl,
    const float* __restrict__ Wg, const float* __restrict__ Wf,
    const float* __restrict__ Wd1, const float* __restrict__ Wd2,
    const float* __restrict__ bh, const float* __restrict__ bl,
    const float* __restrict__ bg, const float* __restrict__ Wup,
    const float* __restrict__ bup, const float* __restrict__ pts,
    ushort* __restrict__ dst, float* __restrict__ fbias,
    float* __restrict__ gridterm) {
  const int which = blockIdx.y;
  int idx = blockIdx.x * 256 + threadIdx.x;
  if (which == 6) {
    if (idx < 384)
      fbias[idx] = idx < 64 ? bh[idx] : (idx < 128 ? bl[idx - 64] : bg[idx - 128]);
    return;
  }
  if (which == 7) {
    if (idx < 2048 * 128) {
      int i = idx >> 7, n = idx & 127;
      gridterm[idx] = bup[n] + pts[2 * i] * Wup[128 * 128 + n]
                             + pts[2 * i + 1] * Wup[129 * 128 + n];
    }
    return;
  }
  if (which == 8) {
    if (idx < 16384) {
      int n = idx >> 7, k = idx & 127;
      dst[294912 + n * 128 + k] = f2b(Wup[k * 128 + n]);
    }
    return;
  }
  const float* src; int K, N; long off;
  switch (which) {
    case 0: src = Wh;  K = 256; N = 64;  off = 0;      break;
    case 1: src = Wl;  K = 256; N = 64;  off = 16384;  break;
    case 2: src = Wg;  K = 256; N = 256; off = 32768;  break;
    case 3: src = Wf;  K = 256; N = 128; off = 98304;  break;
    case 4: src = Wd1; K = 512; N = 256; off = 131072; break;
    default:src = Wd2; K = 256; N = 128; off = 262144; break;
  }
  if (idx >= K * N) return;
  int n = idx / K, k = idx - n * K;
  dst[off + idx] = f2b(src[(long)k * N + n]);
}

// ---------------------------------------------------------------------------
// pconv: p f32 -> pb bf16 [32][512][128]; also writes the 4 tile-repeat
// copies into qcb's q-halves (qcb[b][i+512j][0:128], j=0..3).
// ---------------------------------------------------------------------------
__global__ __launch_bounds__(256) void pconv_kernel(
    const float* __restrict__ p, ushort* __restrict__ pb,
    ushort* __restrict__ qcb) {
  int idx = blockIdx.x * 256 + threadIdx.x;      // 0..524287, 4 elems each
  long base = (long)idx * 4;
  int b = (int)(base >> 16);                     // 512*128 per batch
  int rem = (int)(base & 65535);
  int i = rem >> 7, n = rem & 127;
  float4 v = *(const float4*)(p + base);
  ushort4 u;
  u.x = f2b(v.x); u.y = f2b(v.y); u.z = f2b(v.z); u.w = f2b(v.w);
  *(ushort4*)(pb + base) = u;
#pragma unroll
  for (int j = 0; j < 4; ++j)
    *(ushort4*)(qcb + ((long)b * 2048 + i + 512 * j) * 256 + n) = u;
}

// ---------------------------------------------------------------------------
// MFMA bf16 GEMM v2: BM=128, BN=128, BK=64; 256 threads = 2x2 waves;
// wave tile 64x64 (acc 4x4 f32x4). 16 ds_read_b128 : 32 MFMA per K-step.
//   MODE 0: bf16 row-major out
//   MODE 3: bf16 pmb(outv) = f2b(aux - relu(acc)); + 4 qcb q-half replicas(out2v)
//   MODE 6: qc up-half build: bias = per-row gridterm(aux);
//           outv=qcb up-half; A rows remapped (row>>11)*512+(row&511)
//   MODE 7: fused h|l|g (N=384, BN=128): col0==0 -> hlb (cols>=64 * LOG2E);
//           col0>=128 -> gt per-batch transposed (out2v), d = n-128
//   MODE 8: f32 outv = relu(acc) + b2f(aux as bf16)   (final add, p1b)
// ---------------------------------------------------------------------------
template <int MODE>
__global__ __launch_bounds__(256) void mgemm(
    const ushort* __restrict__ A, const ushort* __restrict__ Wt,
    const float* __restrict__ bias, void* __restrict__ outv,
    void* __restrict__ out2v, const float* __restrict__ aux,
    int M, int N, int K) {
  __shared__ alignas(16) ushort As[128 * 64];
  __shared__ alignas(16) ushort Bs[128 * 64];
  const int tid = threadIdx.x;
  const int w = tid >> 6, lane = tid & 63, g = lane >> 4, c = lane & 15;
  const int wm = w >> 1, wn = w & 1;
  const long row0 = (long)blockIdx.y * 128;
  const int col0 = blockIdx.x * 128;
  const long Astride = (long)K * 2;
  const char* Wb = (const char*)Wt;
  const long abase = (MODE == 6) ? ((row0 >> 11) * 512 + (row0 & 511)) : row0;
  const char* Ab = (const char*)A + abase * Astride;

  f32x4 acc[4][4];
#pragma unroll
  for (int i = 0; i < 4; ++i)
#pragma unroll
    for (int j = 0; j < 4; ++j) acc[i][j] = (f32x4){0.f, 0.f, 0.f, 0.f};

  for (int k0 = 0; k0 < K; k0 += 64) {
#pragma unroll
    for (int it = 0; it < 4; ++it) {
      int o = it * 4096 + tid * 16;
      int row = o >> 7, cb = o & 127;
      gload16(Ab + (long)row * Astride + k0 * 2 + (cb ^ ((row & 7) << 4)),
              (char*)As + o);
    }
#pragma unroll
    for (int it = 0; it < 4; ++it) {
      int o = it * 4096 + tid * 16;
      int row = o >> 7, cb = o & 127;
      gload16(Wb + (long)(col0 + row) * Astride + k0 * 2 + (cb ^ ((row & 7) << 4)),
              (char*)Bs + o);
    }
    __syncthreads();
#pragma unroll
    for (int koff = 0; koff < 2; ++koff) {
      bhalf8 a[4], bfr[4];
#pragma unroll
      for (int mi = 0; mi < 4; ++mi) {
        int row = 64 * wm + 16 * mi + c;
        a[mi] = *(const bhalf8*)((const char*)As + row * 128 +
                                 ((16 * g + 64 * koff) ^ ((row & 7) << 4)));
      }
#pragma unroll
      for (int ni = 0; ni < 4; ++ni) {
        int row = 64 * wn + 16 * ni + c;
        bfr[ni] = *(const bhalf8*)((const char*)Bs + row * 128 +
                                   ((16 * g + 64 * koff) ^ ((row & 7) << 4)));
      }
#pragma unroll
      for (int mi = 0; mi < 4; ++mi)
#pragma unroll
        for (int ni = 0; ni < 4; ++ni)
          acc[mi][ni] = __builtin_amdgcn_mfma_f32_16x16x32_bf16(a[mi], bfr[ni], acc[mi][ni], 0, 0, 0);
    }
    __syncthreads();
  }

#pragma unroll
  for (int ni = 0; ni < 4; ++ni) {
    int n = col0 + 64 * wn + 16 * ni + c;
    float bn = (MODE == 6) ? 0.f : bias[n];
#pragma unroll
    for (int mi = 0; mi < 4; ++mi) {
      long m0 = row0 + 64 * wm + 16 * mi + 4 * g;
      if (MODE == 6) {
        ushort* O = (ushort*)outv;
#pragma unroll
        for (int r = 0; r < 4; ++r) {
          int i2048 = (int)((m0 + r) & 2047);
          float val = fmaxf(acc[mi][ni][r] + aux[i2048 * 128 + n], 0.f);
          O[(m0 + r) * 256 + 128 + n] = f2b(val);
        }
        continue;
      }
      float v[4];
#pragma unroll
      for (int r = 0; r < 4; ++r) v[r] = fmaxf(acc[mi][ni][r] + bn, 0.f);
      if (MODE == 0) {
        ushort* O = (ushort*)outv;
#pragma unroll
        for (int r = 0; r < 4; ++r) O[(m0 + r) * N + n] = f2b(v[r]);
      } else if (MODE == 7) {
        if (col0 == 0) {
          ushort* O = (ushort*)outv;
          float sc = (n >= 64) ? LOG2E : 1.0f;
#pragma unroll
          for (int r = 0; r < 4; ++r) O[(m0 + r) * 128 + n] = f2b(v[r] * sc);
        } else {
          int bb = (int)(m0 >> 11);
          int ml = (int)(m0 & 2047);
          int d = n - 128;
          ushort4 u4;
          u4.x = f2b(v[0]); u4.y = f2b(v[1]); u4.z = f2b(v[2]); u4.w = f2b(v[3]);
          *(ushort4*)((ushort*)out2v + ((long)bb * 256 + d) * 2048 + ml) = u4;
        }
      } else if (MODE == 3) {
        ushort* Opmb = (ushort*)outv;
        ushort* Oqcb = (ushort*)out2v;
#pragma unroll
        for (int r = 0; r < 4; ++r) {
          float val = aux[(m0 + r) * N + n] - v[r];
          ushort uv = f2b(val);
          Opmb[(m0 + r) * 128 + n] = uv;
          long bb = (m0 + r) >> 9;
          int ii = (int)((m0 + r) & 511);
#pragma unroll
          for (int j = 0; j < 4; ++j)
            Oqcb[(bb * 2048 + ii + 512 * j) * 256 + n] = uv;
        }
      } else {  // MODE 8: f32 out = relu(acc) + b2f(p1b)
        float* O = (float*)outv;
        const ushort* auxb = (const ushort*)aux;
#pragma unroll
        for (int r = 0; r < 4; ++r)
          O[(m0 + r) * N + n] = v[r] + b2f(auxb[(m0 + r) * N + n]);
      }
    }
  }
}

// ---------------------------------------------------------------------------
// MFMA flash attention v10 (proven 135us config): 2x LDS reuse,
// wave = 32q x full 256d.
//   qcb[b,n,:] = bf16( qcb[b,n,:] + softmax_m(l[n]·h[m]) @ g )
// Swapped QK^T (S^T, q = lane&15); per-lane softmax; in-register P repack.
// 4 waves x 32 q-rows x all 256 d. H+G^T double-buffered LDS (80KB),
// coalesced global_load_lds prefetch 1 iter ahead, ONE barrier per iter.
// launch_bounds(256,2): occupancy is REGISTER-capped (acc 128 + sacc 32 ->
// ~250 unified regs/wave = 2 waves/SIMD); do NOT request 3 (spills, R12).
// ---------------------------------------------------------------------------
__global__ __launch_bounds__(256, 2) void attn_kernel(
    const ushort* __restrict__ hl, const ushort* __restrict__ gtm,
    ushort* __restrict__ qcb) {
  __shared__ alignas(16) ushort Ht[2][64 * 64];    // [kv][dqk], 8KB each
  __shared__ alignas(16) ushort Gs[2][256 * 64];   // [d][kv],  32KB each

  const int tid = threadIdx.x;
  const int w = tid >> 6, lane = tid & 63, g = lane >> 4, c = lane & 15;
  const int bid = blockIdx.x;
  const int wg = (bid & 7) * 64 + (bid >> 3);      // XCD-contiguous remap (512%8==0)
  const int b = wg >> 4, nb = wg & 15;
  const float THR = 11.0f;                          // log2 units

  bhalf8 la[2][2];
#pragma unroll
  for (int qg = 0; qg < 2; ++qg) {
    const ushort* lrow = hl + ((long)b * SOUT + nb * 128 + 32 * w + 16 * qg + c) * 128 + 64 + 8 * g;
    la[qg][0] = *(const bhalf8*)(lrow);
    la[qg][1] = *(const bhalf8*)(lrow + 32);
  }

  float mold[2] = {-INFINITY, -INFINITY}, srow[2] = {0.f, 0.f};
  f32x4 oacc[16][2];
#pragma unroll
  for (int t = 0; t < 16; ++t)
#pragma unroll
    for (int qg = 0; qg < 2; ++qg) oacc[t][qg] = (f32x4){0.f, 0.f, 0.f, 0.f};

  const char* hlbase = (const char*)(hl + (long)b * SOUT * 128);  // row 256B
  const char* gtb = (const char*)(gtm + (long)b * 256 * 2048);    // row 4096B

  {
#pragma unroll
    for (int it = 0; it < 2; ++it) {
      int o = it * 4096 + tid * 16;
      int row = o >> 7, cb = o & 127;
      gload16(hlbase + row * 256 + (cb ^ ((row & 7) << 4)), (char*)Ht[0] + o);
    }
#pragma unroll
    for (int it = 0; it < 8; ++it) {
      int o = it * 4096 + tid * 16;
      int row = o >> 7, cb = o & 127;
      gload16(gtb + (long)row * 4096 + (cb ^ ((row & 7) << 4)), (char*)Gs[0] + o);
    }
  }
  __syncthreads();

  const int srcA = c + 32 * (g & 1);
  const int srcB = srcA + 16;
  const bool hi = (g >> 1) != 0;

  for (int mb = 0; mb < 32; ++mb) {
    const int buf = mb & 1;

    if (mb < 31) {
#pragma unroll
      for (int it = 0; it < 2; ++it) {
        int o = it * 4096 + tid * 16;
        int row = o >> 7, cb = o & 127;
        gload16(hlbase + ((long)(mb + 1) * 64 + row) * 256 + (cb ^ ((row & 7) << 4)),
                (char*)Ht[buf ^ 1] + o);
      }
#pragma unroll
      for (int it = 0; it < 8; ++it) {
        int o = it * 4096 + tid * 16;
        int row = o >> 7, cb = o & 127;
        gload16(gtb + (long)row * 4096 + (mb + 1) * 128 + (cb ^ ((row & 7) << 4)),
                (char*)Gs[buf ^ 1] + o);
      }
    }

    const char* hcur = (const char*)Ht[buf];
    f32x4 sacc[2][4];
#pragma unroll
    for (int qg = 0; qg < 2; ++qg)
#pragma unroll
      for (int j = 0; j < 4; ++j) sacc[qg][j] = (f32x4){0.f, 0.f, 0.f, 0.f};
#pragma unroll
    for (int j = 0; j < 4; ++j) {
      int row = 16 * j + c;
#pragma unroll
      for (int s = 0; s < 2; ++s) {
        bhalf8 hbf = *(const bhalf8*)(hcur + row * 128 +
                                      ((64 * s + 16 * g) ^ ((c & 7) << 4)));
        sacc[0][j] = __builtin_amdgcn_mfma_f32_16x16x32_bf16(hbf, la[0][s], sacc[0][j], 0, 0, 0);
        sacc[1][j] = __builtin_amdgcn_mfma_f32_16x16x32_bf16(hbf, la[1][s], sacc[1][j], 0, 0, 0);
      }
    }

    bhalf8 pb[2][2];
#pragma unroll
    for (int qg = 0; qg < 2; ++qg) {
      float mloc = sacc[qg][0][0];
#pragma unroll
      for (int j = 0; j < 4; ++j)
#pragma unroll
        for (int r = 0; r < 4; ++r) mloc = fmaxf(mloc, sacc[qg][j][r]);
      mloc = fmaxf(mloc, __shfl_xor(mloc, 16));
      mloc = fmaxf(mloc, __shfl_xor(mloc, 32));
      float mnew = fmaxf(mold[qg], mloc);
      bool keep = (mloc <= mold[qg] + THR);
      float scl = keep ? 1.0f : exp2f(mold[qg] - mnew);
      mold[qg] = keep ? mold[qg] : mnew;

      float psum = 0.f;
#pragma unroll
      for (int j = 0; j < 4; ++j)
#pragma unroll
        for (int r = 0; r < 4; ++r) {
          float e = exp2f(sacc[qg][j][r] - mold[qg]);
          sacc[qg][j][r] = e; psum += e;
        }
      psum += __shfl_xor(psum, 16);
      psum += __shfl_xor(psum, 32);
      srow[qg] = srow[qg] * scl + psum;
      if (!__all(keep)) {
#pragma unroll
        for (int t = 0; t < 16; ++t) {
          oacc[t][qg][0] *= scl; oacc[t][qg][1] *= scl;
          oacc[t][qg][2] *= scl; oacc[t][qg][3] *= scl;
        }
      }

#pragma unroll
      for (int s2 = 0; s2 < 2; ++s2) {
        int j2 = 2 * s2;
        unsigned wA0 = pkt(sacc[qg][j2][0], sacc[qg][j2][1]);
        unsigned wA1 = pkt(sacc[qg][j2][2], sacc[qg][j2][3]);
        unsigned wB0 = pkt(sacc[qg][j2 + 1][0], sacc[qg][j2 + 1][1]);
        unsigned wB1 = pkt(sacc[qg][j2 + 1][2], sacc[qg][j2 + 1][3]);
        unsigned a0A = (unsigned)__shfl((int)wA0, srcA);
        unsigned b0A = (unsigned)__shfl((int)wB0, srcA);
        unsigned a1A = (unsigned)__shfl((int)wA1, srcA);
        unsigned b1A = (unsigned)__shfl((int)wB1, srcA);
        unsigned a0B = (unsigned)__shfl((int)wA0, srcB);
        unsigned b0B = (unsigned)__shfl((int)wB0, srcB);
        unsigned a1B = (unsigned)__shfl((int)wA1, srcB);
        unsigned b1B = (unsigned)__shfl((int)wB1, srcB);
        union { unsigned u[4]; bhalf8 v; } pw;
        pw.u[0] = hi ? b0A : a0A;
        pw.u[1] = hi ? b1A : a1A;
        pw.u[2] = hi ? b0B : a0B;
        pw.u[3] = hi ? b1B : a1B;
        pb[qg][s2] = pw.v;
      }
    }

    const char* gcur = (const char*)Gs[buf];
#pragma unroll
    for (int s2 = 0; s2 < 2; ++s2) {
#pragma unroll
      for (int t = 0; t < 16; ++t) {
        int row = 16 * t + c;
        bhalf8 ga = *(const bhalf8*)(gcur + row * 128 +
                                     ((64 * s2 + 16 * g) ^ ((c & 7) << 4)));
        oacc[t][0] = __builtin_amdgcn_mfma_f32_16x16x32_bf16(ga, pb[0][s2], oacc[t][0], 0, 0, 0);
        oacc[t][1] = __builtin_amdgcn_mfma_f32_16x16x32_bf16(ga, pb[1][s2], oacc[t][1], 0, 0, 0);
      }
    }

    __syncthreads();
  }

#pragma unroll
  for (int qg = 0; qg < 2; ++qg) {
    float inv = 1.0f / srow[qg];
    long qrow = ((long)b * SOUT + nb * 128 + 32 * w + 16 * qg + c) * 256;
#pragma unroll
    for (int t = 0; t < 16; ++t) {
      long addr = qrow + 16 * t + 4 * g;
      ushort4 cur = *(const ushort4*)(qcb + addr);
      cur.x = f2b(b2f(cur.x) + oacc[t][qg][0] * inv);
      cur.y = f2b(b2f(cur.y) + oacc[t][qg][1] * inv);
      cur.z = f2b(b2f(cur.z) + oacc[t][qg][2] * inv);
      cur.w = f2b(b2f(cur.w) + oacc[t][qg][3] * inv);
      *(ushort4*)(qcb + addr) = cur;
    }
  }
}

// ---------------------------------------------------------------------------
extern "C" void kernel_launch(void* const* d_in, const int* in_sizes, int n_in,
                              void* d_out, int out_size, void* d_ws, size_t ws_size,
                              hipStream_t stream) {
  (void)in_sizes; (void)n_in; (void)out_size; (void)ws_size;
  const float* p   = (const float*)d_in[0];
  const float* Wh  = (const float*)d_in[1];
  const float* bh  = (const float*)d_in[2];
  const float* Wl  = (const float*)d_in[3];
  const float* bl  = (const float*)d_in[4];
  const float* Wg  = (const float*)d_in[5];
  const float* bg  = (const float*)d_in[6];
  const float* Wf  = (const float*)d_in[7];
  const float* bf  = (const float*)d_in[8];
  const float* Wup = (const float*)d_in[9];
  const float* bup = (const float*)d_in[10];
  const float* Wd1 = (const float*)d_in[11];
  const float* bd1 = (const float*)d_in[12];
  const float* Wd2 = (const float*)d_in[13];
  const float* bd2 = (const float*)d_in[14];
  const int* mArr  = (const int*)d_in[15];
  const int* nArr  = (const int*)d_in[16];
  float* out = (float*)d_out;

  // workspace layout
  float* ws       = (float*)d_ws;
  float* pts      = ws;                         // 4,096 f32
  float* bhlg     = ws + 4096;                  // 512 f32 (384 used)
  float* gridterm = bhlg + 512;                 // 262,144 f32
  ushort* qcb  = (ushort*)(gridterm + 262144);  // 16,777,216 us
  ushort* hlb  = qcb + 16777216;                //  8,388,608 us
  ushort* gt   = hlb + 8388608;                 // 16,777,216 us
  ushort* p1b  = gt + 16777216;                 //  8,388,608 us
  ushort* d1b  = p1b + 8388608;                 //  4,194,304 us
  ushort* pb   = d1b + 4194304;                 //  2,097,152 us
  ushort* pmb  = pb + 2097152;                  //  2,097,152 us
  ushort* wts  = pmb + 2097152;                 //    311,296 us
  ushort* Wft  = wts + 98304;
  ushort* Wd1t = wts + 131072;
  ushort* Wd2t = wts + 262144;
  ushort* Wupt = wts + 294912;

  pts_kernel<<<8, 256, 0, stream>>>(mArr, nArr, pts);
  wconv_kernel<<<dim3(1024, 9), 256, 0, stream>>>(
      Wh, Wl, Wg, Wf, Wd1, Wd2, bh, bl, bg, Wup, bup, pts, wts, bhlg, gridterm);

  // ---------------- up #1 ----------------
  pconv_kernel<<<2048, 256, 0, stream>>>(p, pb, qcb);
  mgemm<6><<<dim3(1, 512), 256, 0, stream>>>(pb, Wupt, bhlg, qcb, nullptr, gridterm, 65536, 128, 128);
  mgemm<7><<<dim3(3, 512), 256, 0, stream>>>(qcb, wts, bhlg, hlb, gt, nullptr, 65536, 384, 256);
  attn_kernel<<<512, 256, 0, stream>>>(hlb, gt, qcb);
  mgemm<0><<<dim3(1, 512), 256, 0, stream>>>(qcb, Wft, bf, p1b, nullptr, nullptr, 65536, 128, 256);

  // ---------------- down ----------------
  mgemm<0><<<dim3(2, 128), 256, 0, stream>>>(p1b, Wd1t, bd1, d1b, nullptr, nullptr, 16384, 256, 512);
  mgemm<3><<<dim3(1, 128), 256, 0, stream>>>(d1b, Wd2t, bd2, pmb, qcb, p, 16384, 128, 256);

  // ---------------- up #2 + final add ----------------
  mgemm<6><<<dim3(1, 512), 256, 0, stream>>>(pmb, Wupt, bhlg, qcb, nullptr, gridterm, 65536, 128, 128);
  mgemm<7><<<dim3(3, 512), 256, 0, stream>>>(qcb, wts, bhlg, hlb, gt, nullptr, 65536, 384, 256);
  attn_kernel<<<512, 256, 0, stream>>>(hlb, gt, qcb);
  mgemm<8><<<dim3(1, 512), 256, 0, stream>>>(qcb, Wft, bf, out, nullptr, (const float*)p1b, 65536, 128, 256);
}